// Round 1
// baseline (1273.990 us; speedup 1.0000x reference)
//
#include <hip/hip_runtime.h>

// PNLM: patch (15x15) non-local attention + projection + residual.
// k_qk  : QT/KT[b][hw][160] bf16 (per-pixel projections) into d_ws (295 MB).
// k_attn: per patch block: att^T via MFMA, lane-local softmax, PV, proj, +x.

typedef __bf16 bf16x8 __attribute__((ext_vector_type(8)));
typedef float  f32x4  __attribute__((ext_vector_type(4)));

#define MFMA(a,b,c) __builtin_amdgcn_mfma_f32_16x16x32_bf16((a),(b),(c),0,0,0)

__device__ __forceinline__ unsigned short f2bf(float f){
  union { float f; unsigned int u; } v; v.f = f;
  unsigned int r = v.u + 0x7FFFu + ((v.u >> 16) & 1u);   // RNE
  return (unsigned short)(r >> 16);
}
__device__ __forceinline__ float bf2f(unsigned short u){
  union { unsigned int u; float f; } v; v.u = ((unsigned int)u) << 16;
  return v.f;
}
// All LDS tiles are [rows][256] bf16 with 16B-block XOR swizzle (write & read
// use the SAME involution -> correctness independent of bank analysis).
__device__ __forceinline__ int swz(int row, int col){
  return row*256 + ((((col >> 3) ^ (row & 7)) << 3) | (col & 7));
}
__device__ __forceinline__ bf16x8 ld_frag_lds(const unsigned short* p, int idx){
  uint4 v = *(const uint4*)(p + idx);
  return __builtin_bit_cast(bf16x8, v);
}
__device__ __forceinline__ bf16x8 ld_frag_glb(const unsigned short* p){
  uint4 v = *(const uint4*)p;
  return __builtin_bit_cast(bf16x8, v);
}

// D-layout (col=lane&15, rows=4*(lane>>4)+jj per 16-tile T) -> operand-frag
// layout (same lane&15 index, k = 8*(lane>>4)+j over 32-chunks).
// plo[T] = rows{0,1} packed bf16, phi[T] = rows{2,3}. Arrays length 16.
__device__ __forceinline__ void repack_frag(const unsigned int* plo, const unsigned int* phi,
                                            uint4* outf, int lane){
  const int nn = lane & 15, hh = lane >> 4;
  const int sla = nn + 32*(hh & 1);
  const int slb = sla + 16;
  const bool up = hh >= 2;              // T' = 2k + (hh>>1)
  #pragma unroll
  for (int k = 0; k < 8; ++k){
    unsigned int a0 = (unsigned int)__shfl((int)plo[2*k],   sla);
    unsigned int a1 = (unsigned int)__shfl((int)plo[2*k+1], sla);
    unsigned int b0 = (unsigned int)__shfl((int)phi[2*k],   sla);
    unsigned int b1 = (unsigned int)__shfl((int)phi[2*k+1], sla);
    unsigned int c0 = (unsigned int)__shfl((int)plo[2*k],   slb);
    unsigned int c1 = (unsigned int)__shfl((int)plo[2*k+1], slb);
    unsigned int d0 = (unsigned int)__shfl((int)phi[2*k],   slb);
    unsigned int d1 = (unsigned int)__shfl((int)phi[2*k+1], slb);
    outf[k] = make_uint4(up?a1:a0, up?b1:b0, up?c1:c0, up?d1:d0);
  }
}

// ---------------- kernel 1: QT/KT projections --------------------------------
__global__ __launch_bounds__(512) void k_qk(
    const float* __restrict__ x, const float* __restrict__ wq,
    const float* __restrict__ wk,
    unsigned short* __restrict__ qws, unsigned short* __restrict__ kws)
{
  __shared__ unsigned short xt [128*256];  // X^T tile [hw][c], swizzled
  __shared__ unsigned short wqs[ 32*256];  // wq rows  [e ][c], swizzled
  __shared__ unsigned short wks[ 32*256];
  const int wg  = blockIdx.x;
  const int b   = wg / 450;
  const int hw0 = (wg % 450) * 128;
  const int tid = threadIdx.x;
  const int lane = tid & 63, wave = tid >> 6;
  const int col  = lane & 15, hi = lane >> 4;

  { // stage X^T (fp32 -> bf16), coalesced reads over hw
    const float* xb = x + (size_t)b * 256 * 57600 + hw0;
    const int hw_l = tid & 127;
    #pragma unroll 4
    for (int i = 0; i < 32; ++i){
      int cp = (tid >> 7) * 32 + i;      // 0..127
      int c  = cp * 2;
      float f0 = xb[(size_t)c     * 57600 + hw_l];
      float f1 = xb[(size_t)(c+1) * 57600 + hw_l];
      *(unsigned int*)(&xt[swz(hw_l, c)]) =
          (unsigned int)f2bf(f0) | ((unsigned int)f2bf(f1) << 16);
    }
  }
  __syncthreads();

  bf16x8 af[8];                          // A-frags: this wave's 16 hw rows
  const int arow = wave*16 + col;
  #pragma unroll
  for (int k = 0; k < 8; ++k)
    af[k] = ld_frag_lds(xt, swz(arow, k*32 + hi*8));

  const size_t orow_base = (size_t)b*57600 + hw0 + wave*16;

  for (int eg = 0; eg < 5; ++eg){        // e-groups of 32 (e_pad=160, zeros>=144)
    __syncthreads();
    for (int i = 0; i < 8; ++i){
      int idx = tid + i*512;             // 0..4095
      int e_l = idx >> 7, c = (idx & 127) * 2;
      int e = eg*32 + e_l;
      float2 vq = make_float2(0.f,0.f), vk = make_float2(0.f,0.f);
      if (e < 144){
        vq = *(const float2*)(wq + (size_t)e*256 + c);
        vk = *(const float2*)(wk + (size_t)e*256 + c);
      }
      *(unsigned int*)(&wqs[swz(e_l, c)]) =
          (unsigned int)f2bf(vq.x) | ((unsigned int)f2bf(vq.y) << 16);
      *(unsigned int*)(&wks[swz(e_l, c)]) =
          (unsigned int)f2bf(vk.x) | ((unsigned int)f2bf(vk.y) << 16);
    }
    __syncthreads();
    #pragma unroll
    for (int etl = 0; etl < 2; ++etl){
      f32x4 aq = {0.f,0.f,0.f,0.f}, ak = {0.f,0.f,0.f,0.f};
      const int el = etl*16 + col;
      #pragma unroll
      for (int k = 0; k < 8; ++k){
        int idx = swz(el, k*32 + hi*8);
        bf16x8 bq = ld_frag_lds(wqs, idx);
        bf16x8 bk = ld_frag_lds(wks, idx);
        aq = MFMA(af[k], bq, aq);
        ak = MFMA(af[k], bk, ak);
      }
      const int e_out = eg*32 + etl*16 + col;
      #pragma unroll
      for (int jj = 0; jj < 4; ++jj){
        size_t row = orow_base + hi*4 + jj;
        qws[row*160 + e_out] = f2bf(aq[jj]);
        kws[row*160 + e_out] = f2bf(ak[jj]);
      }
    }
  }
}

// ---------------- kernel 2: attention + PV + proj + residual -----------------
__global__ __launch_bounds__(512) void k_attn(
    const float* __restrict__ x, const float* __restrict__ wproj,
    const unsigned short* __restrict__ qws, const unsigned short* __restrict__ kws,
    float* __restrict__ out)
{
  __shared__ unsigned short big [256*256]; // phase A: KT[240][256]; phase B: X[c][m]
  __shared__ unsigned short wlds[ 32*256]; // wproj eighth
  const int wg = blockIdx.x;
  const int b  = wg >> 8;
  const int th = (wg >> 4) & 15, tw = wg & 15;
  const int h0 = th*15, w0 = tw*15;
  const int tid = threadIdx.x;
  const int lane = tid & 63, wave = tid >> 6;
  const int col  = lane & 15, hi = lane >> 4;
  const size_t xbase = (size_t)b * 256 * 57600;

  // ---- P0: stage KT patch rows (m 0..239, clamped >224) ----
  for (int i = tid; i < 240*20; i += 512){
    int m  = i / 20, eb = i % 20;
    int ms = m <= 224 ? m : 224;
    int hw = (h0 + ms/15)*240 + w0 + ms%15;
    uint4 v = *(const uint4*)(kws + ((size_t)b*57600 + hw)*160 + eb*8);
    *(uint4*)(&big[swz(m, eb*8)]) = v;
  }
  __syncthreads();

  // ---- P1: att^T strips + lane-local softmax + register repack ----
  uint4 attf[2][8];
  #pragma unroll
  for (int slot = 0; slot < 2; ++slot){
    const int nt = wave + slot*8;
    if (nt < 15){
      const int n  = nt*16 + col;
      const int na = n <= 224 ? n : 224;          // clamp (garbage cols unused)
      const int hwq = (h0 + na/15)*240 + w0 + na%15;
      const unsigned short* qrow = qws + ((size_t)b*57600 + hwq)*160;
      bf16x8 qf[5];
      #pragma unroll
      for (int c = 0; c < 5; ++c)
        qf[c] = ld_frag_glb(qrow + c*32 + hi*8);
      f32x4 at[15];
      #pragma unroll
      for (int T = 0; T < 15; ++T){
        f32x4 acc = {0.f,0.f,0.f,0.f};
        #pragma unroll
        for (int c = 0; c < 5; ++c){
          bf16x8 kf = ld_frag_lds(big, swz(T*16 + col, c*32 + hi*8));
          acc = MFMA(kf, qf[c], acc);             // att^T[m][n]
        }
        at[T] = acc;
      }
      const float sc = 0.12022458674074695f;      // log2(e)/12
      float M = -3.0e38f;
      #pragma unroll
      for (int T = 0; T < 15; ++T){
        #pragma unroll
        for (int jj = 0; jj < 4; ++jj){
          int m = T*16 + hi*4 + jj;
          if (m <= 224) M = fmaxf(M, at[T][jj]*sc);
        }
      }
      M = fmaxf(M, __shfl_xor(M, 16));
      M = fmaxf(M, __shfl_xor(M, 32));
      float S = 0.f;
      #pragma unroll
      for (int T = 0; T < 15; ++T){
        #pragma unroll
        for (int jj = 0; jj < 4; ++jj){
          int m = T*16 + hi*4 + jj;
          float v = (m <= 224) ? exp2f(at[T][jj]*sc - M) : 0.f;
          at[T][jj] = v; S += v;
        }
      }
      S += __shfl_xor(S, 16);
      S += __shfl_xor(S, 32);
      const float inv = 1.0f / S;
      unsigned int plo[16], phi[16];
      #pragma unroll
      for (int T = 0; T < 15; ++T){
        plo[T] = (unsigned int)f2bf(at[T][0]*inv) | ((unsigned int)f2bf(at[T][1]*inv) << 16);
        phi[T] = (unsigned int)f2bf(at[T][2]*inv) | ((unsigned int)f2bf(at[T][3]*inv) << 16);
      }
      plo[15] = 0u; phi[15] = 0u;
      repack_frag(plo, phi, attf[slot], lane);
    }
  }
  __syncthreads();   // KT dead

  // ---- P2: stage X[c][m] bf16 (m 225..255 zero) ----
  for (int i = tid; i < 256*128; i += 512){
    int c = i >> 7, m = (i & 127) * 2;
    float f0 = 0.f, f1 = 0.f;
    if (m     <= 224) f0 = x[xbase + (size_t)c*57600 + (h0 + m/15)*240 + w0 + m%15];
    if (m + 1 <= 224) f1 = x[xbase + (size_t)c*57600 + (h0 + (m+1)/15)*240 + w0 + (m+1)%15];
    *(unsigned int*)(&big[swz(c, m)]) =
        (unsigned int)f2bf(f0) | ((unsigned int)f2bf(f1) << 16);
  }
  __syncthreads();

  // ---- P3: PV  y1[c][n] = sum_m X[c][m] * P[n][m] ----
  uint4 y1f[2][8];
  #pragma unroll
  for (int slot = 0; slot < 2; ++slot){
    const int nt = wave + slot*8;
    if (nt < 15){
      unsigned int ylo[16], yhi[16];
      #pragma unroll
      for (int ct = 0; ct < 16; ++ct){
        f32x4 acc = {0.f,0.f,0.f,0.f};
        #pragma unroll
        for (int k = 0; k < 8; ++k){
          bf16x8 xf = ld_frag_lds(big, swz(ct*16 + col, k*32 + hi*8));
          acc = MFMA(xf, __builtin_bit_cast(bf16x8, attf[slot][k]), acc);
        }
        ylo[ct] = (unsigned int)f2bf(acc[0]) | ((unsigned int)f2bf(acc[1]) << 16);
        yhi[ct] = (unsigned int)f2bf(acc[2]) | ((unsigned int)f2bf(acc[3]) << 16);
      }
      repack_frag(ylo, yhi, y1f[slot], lane);
    }
  }

  // ---- P4: projection (wproj in 32-row LDS eighths) + residual + store ----
  for (int oe = 0; oe < 8; ++oe){
    __syncthreads();
    for (int i = tid; i < 32*128; i += 512){
      int ol = i >> 7, c = (i & 127) * 2;
      float2 v = *(const float2*)(wproj + (size_t)(oe*32 + ol)*256 + c);
      *(unsigned int*)(&wlds[swz(ol, c)]) =
          (unsigned int)f2bf(v.x) | ((unsigned int)f2bf(v.y) << 16);
    }
    __syncthreads();
    #pragma unroll
    for (int ot = 0; ot < 2; ++ot){
      bf16x8 awf[8];
      const int ol = ot*16 + col;
      #pragma unroll
      for (int k = 0; k < 8; ++k)
        awf[k] = ld_frag_lds(wlds, swz(ol, k*32 + hi*8));
      #pragma unroll
      for (int slot = 0; slot < 2; ++slot){
        const int nt = wave + slot*8;
        if (nt < 15){
          f32x4 y2 = {0.f,0.f,0.f,0.f};
          #pragma unroll
          for (int k = 0; k < 8; ++k)
            y2 = MFMA(awf[k], __builtin_bit_cast(bf16x8, y1f[slot][k]), y2);
          const int n = nt*16 + col;
          if (n <= 224){
            const int r = n/15, s = n%15;
            const size_t pix = (size_t)(h0 + r)*240 + w0 + s;
            #pragma unroll
            for (int jj = 0; jj < 4; ++jj){
              int o = oe*32 + ot*16 + hi*4 + jj;
              float xr = bf2f(big[swz(o, n)]);    // residual (bf16 x)
              out[xbase + (size_t)o*57600 + pix] = y2[jj] + xr;
            }
          }
        }
      }
    }
  }
}

extern "C" void kernel_launch(void* const* d_in, const int* in_sizes, int n_in,
                              void* d_out, int out_size, void* d_ws, size_t ws_size,
                              hipStream_t stream)
{
  const float* x     = (const float*)d_in[0];
  const float* wq    = (const float*)d_in[1];
  const float* wk    = (const float*)d_in[2];
  const float* wproj = (const float*)d_in[3];
  float* out = (float*)d_out;
  // workspace: QT then KT, each 8*57600 rows * 160 bf16 = 147,456,000 B
  unsigned short* qws = (unsigned short*)d_ws;
  unsigned short* kws = qws + (size_t)8*57600*160;
  (void)in_sizes; (void)n_in; (void)out_size; (void)ws_size;

  k_qk  <<<dim3(3600), dim3(512), 0, stream>>>(x, wq, wk, qws, kws);
  k_attn<<<dim3(2048), dim3(512), 0, stream>>>(x, wproj, qws, kws, out);
}